// Round 14
// baseline (1202.127 us; speedup 1.0000x reference)
//
#include <hip/hip_runtime.h>
#include <math.h>

// Problem constants: EMBED=256, HEADS=8, LEVELS=1, POINTS=4, QUEUE=2, 200x200
#define NQ    40000
#define EMB   256
#define NHEAD 8
#define HDIM  32
#define HB    200
#define WB    200
#define NCOL  192     // 128 off cols + 64 aw cols
#define HPIX  2560000 // per-head vout plane: 80000 pixels * 32 dims
#define GRID  1280    // persistent grid: 5 blocks/CU (capacity 8/CU at 64 VGPR,
                      // 16.9 KB LDS -> co-residency guaranteed, 1.6x margin)

typedef __attribute__((ext_vector_type(8))) __bf16 bf16x8;
typedef __attribute__((ext_vector_type(4))) float f32x4;

static __device__ __forceinline__ unsigned short f2bf(float f) {
  unsigned u = __float_as_uint(f);
  u = u + 0x7fffu + ((u >> 16) & 1u);   // round-to-nearest-even
  return (unsigned short)(u >> 16);
}
static __device__ __forceinline__ float bf2f(unsigned short s) {
  return __uint_as_float(((unsigned)s) << 16);
}
// accumulate 8 bf16 (one uint4) into two named float4s (spill-safe)
static __device__ __forceinline__ void accp(float4& lo4, float4& hi4, uint4 u, float w) {
  lo4.x += w * __uint_as_float(u.x << 16);
  lo4.y += w * __uint_as_float(u.x & 0xffff0000u);
  lo4.z += w * __uint_as_float(u.y << 16);
  lo4.w += w * __uint_as_float(u.y & 0xffff0000u);
  hi4.x += w * __uint_as_float(u.z << 16);
  hi4.y += w * __uint_as_float(u.z & 0xffff0000u);
  hi4.z += w * __uint_as_float(u.w << 16);
  hi4.w += w * __uint_as_float(u.w & 0xffff0000u);
}

// ---------------------------------------------------------------------------
// grid_sync: manual all-blocks barrier (monotonic counter, reset to 0 by a
// hipMemsetAsync before each launch -> graph-replay / re-poison safe).
// Device-scope atomics + __threadfence for cross-XCD visibility (G16).
// Safe because GRID (1280) <= guaranteed co-resident capacity (2048).
// ---------------------------------------------------------------------------
static __device__ __forceinline__ void grid_sync(unsigned* bar) {
  __syncthreads();
  if (threadIdx.x == 0) {
    __threadfence();                       // publish this block's writes
    unsigned my = atomicAdd(bar, 1u) + 1u;
    unsigned tgt = ((my - 1u) / (unsigned)GRID + 1u) * (unsigned)GRID;
    while (atomicAdd(bar, 0u) < tgt) { __builtin_amdgcn_s_sleep(16); }
    __threadfence();                       // acquire others' writes
  }
  __syncthreads();
}

// ---------------------------------------------------------------------------
// conv body: transposed bf16 weights + combined bias (coalesced reads)
// ---------------------------------------------------------------------------
static __device__ __forceinline__ void conv_body(
    int tile, int t,
    const float* __restrict__ W_off, const float* __restrict__ b_off,
    const float* __restrict__ W_attn, const float* __restrict__ b_attn,
    const float* __restrict__ W_val, const float* __restrict__ W_out,
    unsigned short* __restrict__ Wc1t, unsigned short* __restrict__ Wvt,
    unsigned short* __restrict__ Wot, float* __restrict__ bc1)
{
  int idx = tile * 256 + t;
  if (idx < 65536) {                       // W_off [512][128] -> Wc1t[n][k]
    int k = idx >> 7, n = idx & 127;
    Wc1t[(size_t)n * 512 + k] = f2bf(W_off[idx]);
  } else if (idx < 98304) {                // W_attn [512][64] -> Wc1t[128+n][k]
    int j = idx - 65536;
    int k = j >> 6, n = j & 63;
    Wc1t[(size_t)(128 + n) * 512 + k] = f2bf(W_attn[j]);
  } else if (idx < 163840) {               // W_val [256][256] -> Wvt[n][k]
    int j = idx - 98304;
    int k = j >> 8, n = j & 255;
    Wvt[(size_t)n * 256 + k] = f2bf(W_val[j]);
  } else if (idx < 229376) {               // W_out [256][256] -> Wot[n][k]
    int j = idx - 163840;
    int k = j >> 8, n = j & 255;
    Wot[(size_t)n * 256 + k] = f2bf(W_out[j]);
  } else if (idx < 229568) {               // bc1 [192]
    int n = idx - 229376;
    bc1[n] = (n < 128) ? b_off[n] : b_attn[n - 128];
  }
}

// ---------------------------------------------------------------------------
// GEMM body (round-12/13 verified, BM=32). C[32 x N] = A @ Bt^T + bias.
// Block = 4 waves 1m x 4n. Staged A: 32x256 bf16 LDS half-tile (16.4 KB),
// XOR-swizzled 16B chunks (slot = c ^ (r&7)); K=512 stages two halves.
// Staged sources are [M][256] fp32: stride 256 ALWAYS (hh selects WHICH
// tensor, never a column offset — round-11 lesson).
// AMODE 1 = fp32 staged; 2 = synth q2 staged (half0 value, half1 q+qp);
// 0 = bf16 [M][K] direct; 4 = bf16 head-major [h][NQ][32] direct.
// OMODE 0 = fp32 direct (+resid); 1 = bf16 row-major; 2 = bf16 head-major.
// BM=32 stays (round-10: BM=16 doubled B-load per MFMA).
// ---------------------------------------------------------------------------
template<int K, int N, int AMODE, int OMODE, bool RESID>
static __device__ __forceinline__ void gemm_body(
    int bx, char* lds,
    const void* __restrict__ Aptr, const void* __restrict__ Aq2a,
    const void* __restrict__ Aq2b, const unsigned short* __restrict__ Bt,
    const float* __restrict__ bias, const float* __restrict__ resid,
    void* __restrict__ outp)
{
  constexpr int NFR = N / 64;              // 16-col n-frags per wave
  constexpr int NP  = N + 8;
  unsigned short* trn = (unsigned short*)lds;

  const int t = threadIdx.x;
  const int m0 = bx * 32;
  const int wid = t >> 6, lane = t & 63;
  const int wn = wid * (N / 4);
  const int lr = lane & 15, quad = lane >> 4;

  auto cvt_store = [&](int r, int c, float4 f0, float4 f1) {
    union { unsigned short us[8]; uint4 v; } u;
    u.us[0] = f2bf(f0.x); u.us[1] = f2bf(f0.y);
    u.us[2] = f2bf(f0.z); u.us[3] = f2bf(f0.w);
    u.us[4] = f2bf(f1.x); u.us[5] = f2bf(f1.y);
    u.us[6] = f2bf(f1.z); u.us[7] = f2bf(f1.w);
    *(uint4*)(lds + (size_t)r * 512 + ((c ^ (r & 7)) * 16)) = u.v;
  };

  // stage one 256-wide K-half (hh): thread owns col-chunk c = t&31,
  // rows r0 + 8l; ALL loads issued before any convert (one HBM exposure).
  auto stage_h = [&](int hh) {
    const int c = t & 31, r0 = t >> 5;
    if (AMODE == 1 || hh == 0) {
      float4 f[4][2];
      #pragma unroll
      for (int l = 0; l < 4; l++) {
        const float* s = (const float*)Aptr
            + (size_t)(m0 + r0 + 8 * l) * 256 + c * 8;
        f[l][0] = *(const float4*)s; f[l][1] = *(const float4*)(s + 4);
      }
      #pragma unroll
      for (int l = 0; l < 4; l++)
        cvt_store(r0 + 8 * l, c, f[l][0], f[l][1]);
    } else {
      float4 fq[4][2], fp[4][2];
      #pragma unroll
      for (int l = 0; l < 4; l++) {
        int row = m0 + r0 + 8 * l;
        const float* sq = (const float*)Aq2a + (size_t)row * 256 + c * 8;
        const float* sp = (const float*)Aq2b + (size_t)row * 256 + c * 8;
        fq[l][0] = *(const float4*)sq; fq[l][1] = *(const float4*)(sq + 4);
        fp[l][0] = *(const float4*)sp; fp[l][1] = *(const float4*)(sp + 4);
      }
      #pragma unroll
      for (int l = 0; l < 4; l++) {
        float4 f0 = make_float4(fq[l][0].x + fp[l][0].x, fq[l][0].y + fp[l][0].y,
                                fq[l][0].z + fp[l][0].z, fq[l][0].w + fp[l][0].w);
        float4 f1 = make_float4(fq[l][1].x + fp[l][1].x, fq[l][1].y + fp[l][1].y,
                                fq[l][1].z + fp[l][1].z, fq[l][1].w + fp[l][1].w);
        cvt_store(r0 + 8 * l, c, f0, f1);
      }
    }
  };

  f32x4 acc[2][NFR];
  #pragma unroll
  for (int i = 0; i < 2; i++)
    #pragma unroll
    for (int n = 0; n < NFR; n++) acc[i][n] = (f32x4){0.f, 0.f, 0.f, 0.f};

  auto loadB = [&](bf16x8* dst, int k0) {  // k0 = global K offset
    #pragma unroll
    for (int n = 0; n < NFR; n++)
      dst[n] = *(const bf16x8*)(Bt + (size_t)(wn + n * 16 + lr) * K + k0 + quad * 8);
  };
  auto loadA_lds = [&](bf16x8* dst, int lk) {  // lk = offset within half
    const int cb = (lk >> 3) + quad;
    const int sw = (cb ^ (lr & 7)) * 16;
    #pragma unroll
    for (int i = 0; i < 2; i++)
      dst[i] = *(const bf16x8*)(lds + (size_t)(lr + i * 16) * 512 + sw);
  };
  auto loadA_dir = [&](bf16x8* dst, int k0) {
    if constexpr (AMODE == 0) {
      const unsigned short* A = (const unsigned short*)Aptr;
      #pragma unroll
      for (int i = 0; i < 2; i++)
        dst[i] = *(const bf16x8*)(A + (size_t)(m0 + lr + i * 16) * K + k0 + quad * 8);
    } else {                               // AMODE == 4: head-major
      const unsigned short* A = (const unsigned short*)Aptr;
      const int h = k0 >> 5;
      #pragma unroll
      for (int i = 0; i < 2; i++)
        dst[i] = *(const bf16x8*)(A + (size_t)h * NQ * 32
                                    + (size_t)(m0 + lr + i * 16) * 32 + quad * 8);
    }
  };

  if constexpr (AMODE == 1 || AMODE == 2) {
    constexpr int NH = K / 256;            // staged halves
    #pragma unroll
    for (int hh = 0; hh < NH; hh++) {
      if (hh) __syncthreads();             // WAR: prev half reads done
      stage_h(hh);
      __syncthreads();
      bf16x8 b0[NFR], b1[NFR], af[2];
      loadB(b0, hh * 256);
      loadB(b1, hh * 256 + 32);
      loadA_lds(af, 0);
      #pragma unroll
      for (int ks = 0; ks < 8; ks++) {
        bf16x8 b2[NFR], an[2];
        if (ks + 2 < 8) loadB(b2, hh * 256 + (ks + 2) * 32);
        if (ks + 1 < 8) loadA_lds(an, (ks + 1) * 32);
        #pragma unroll
        for (int i = 0; i < 2; i++)
          #pragma unroll
          for (int n = 0; n < NFR; n++)
            acc[i][n] = __builtin_amdgcn_mfma_f32_16x16x32_bf16(af[i], b0[n], acc[i][n], 0, 0, 0);
        #pragma unroll
        for (int n = 0; n < NFR; n++) { b0[n] = b1[n]; b1[n] = b2[n]; }
        af[0] = an[0]; af[1] = an[1];
      }
    }
  } else {
    constexpr int NK = K / 32;
    bf16x8 b0[NFR], b1[NFR], af[2];
    loadB(b0, 0);
    if (NK > 1) loadB(b1, 32);
    loadA_dir(af, 0);
    #pragma unroll
    for (int ks = 0; ks < NK; ks++) {
      bf16x8 b2[NFR], an[2];
      if (ks + 2 < NK) loadB(b2, (ks + 2) * 32);
      if (ks + 1 < NK) loadA_dir(an, (ks + 1) * 32);
      #pragma unroll
      for (int i = 0; i < 2; i++)
        #pragma unroll
        for (int n = 0; n < NFR; n++)
          acc[i][n] = __builtin_amdgcn_mfma_f32_16x16x32_bf16(af[i], b0[n], acc[i][n], 0, 0, 0);
      #pragma unroll
      for (int n = 0; n < NFR; n++) { b0[n] = b1[n]; b1[n] = b2[n]; }
      af[0] = an[0]; af[1] = an[1];
    }
  }

  // epilogue: C/D layout col=lane&15, row=quad*4+reg
  if constexpr (OMODE == 0) {
    #pragma unroll
    for (int i = 0; i < 2; i++) {
      int rowb = m0 + i * 16 + quad * 4;
      #pragma unroll
      for (int n = 0; n < NFR; n++) {
        int col = wn + n * 16 + lr;
        float bsv = bias[col];
        #pragma unroll
        for (int r = 0; r < 4; r++) {
          int rr = rowb + r;
          float v = acc[i][n][r] + bsv;
          if (RESID) v += resid[(size_t)rr * N + col];
          ((float*)outp)[(size_t)rr * N + col] = v;
        }
      }
    }
  } else {
    __syncthreads();                       // A-tile -> trn buffer reuse
    #pragma unroll
    for (int i = 0; i < 2; i++) {
      #pragma unroll
      for (int n = 0; n < NFR; n++) {
        int col = wn + n * 16 + lr;
        float bsv = bias[col];
        #pragma unroll
        for (int r = 0; r < 4; r++) {
          int rl = i * 16 + quad * 4 + r;
          trn[rl * NP + col] = f2bf(acc[i][n][r] + bsv);
        }
      }
    }
    __syncthreads();
    constexpr int NCH = (32 * N) / 2048;   // uint4 chunks per thread
    #pragma unroll
    for (int l = 0; l < NCH; l++) {
      int c = t + l * 256;
      int row = c / (N / 8);
      int coloff = (c % (N / 8)) * 8;
      uint4 d = *(const uint4*)(trn + row * NP + coloff);
      unsigned short* op = (unsigned short*)outp;
      if constexpr (OMODE == 2)
        op += (size_t)(coloff >> 5) * HPIX + (size_t)(m0 + row) * 32 + (coloff & 31);
      else
        op += (size_t)(m0 + row) * N + coloff;
      *(uint4*)op = d;
    }
  }
}

// ---------------------------------------------------------------------------
// k3 body: deformable sampling + queue mean, HEAD<->XCD AFFINE (round-8
// verified). tile = qg*8 + h; with GRID % 8 == 0 the grid-stride keeps
// h = bid&7 constant per block -> per-XCD 5 MB head plane stays L2-affine.
// sidx/swgt live in the caller's LDS buffer (16 KB <= 16.9 KB).
// ---------------------------------------------------------------------------
static __device__ __forceinline__ void k3_body(
    int tile, char* lds,
    const unsigned short* __restrict__ raw1, const float* __restrict__ refp,
    const unsigned short* __restrict__ vh, unsigned short* __restrict__ msd)
{
  int4*   sidx = (int4*)lds;               // [512] = 8 KB
  float4* swgt = (float4*)(lds + 8192);    // [512] = 8 KB
  const int t = threadIdx.x;
  const int h  = tile & 7;                 // head = XCD slot
  const int q0 = (tile >> 3) * 64;         // 625 query-groups x 8 heads

  #pragma unroll
  for (int ee = 0; ee < 2; ee++) {
    const int e = t + ee * 256;            // e = qi*8 + b*4 + p
    const int qi = e >> 3, b = (e >> 2) & 1, p = e & 3;
    const int q = q0 + qi;
    const unsigned short* r = raw1 + (size_t)q * NCOL;
    float ox = bf2f(r[h * 16 + b * 8 + p * 2 + 0]);
    float oy = bf2f(r[h * 16 + b * 8 + p * 2 + 1]);
    float l0 = bf2f(r[128 + h * 8 + b * 4 + 0]);
    float l1 = bf2f(r[128 + h * 8 + b * 4 + 1]);
    float l2 = bf2f(r[128 + h * 8 + b * 4 + 2]);
    float l3 = bf2f(r[128 + h * 8 + b * 4 + 3]);
    float mx = fmaxf(fmaxf(l0, l1), fmaxf(l2, l3));
    float e0 = expf(l0 - mx), e1 = expf(l1 - mx);
    float e2 = expf(l2 - mx), e3 = expf(l3 - mx);
    float ssum = e0 + e1 + e2 + e3;
    float ep = (p == 0) ? e0 : (p == 1) ? e1 : (p == 2) ? e2 : e3;
    float aw = ep / ssum * 0.5f;           // fold queue-mean 0.5
    float rx = refp[((size_t)b * NQ + q) * 2 + 0];
    float ry = refp[((size_t)b * NQ + q) * 2 + 1];
    float px = rx * (float)WB + ox - 0.5f;
    float py = ry * (float)HB + oy - 0.5f;
    float x0f = floorf(px), y0f = floorf(py);
    float lx = px - x0f, ly = py - y0f;
    int x0 = (int)x0f, y0 = (int)y0f, x1 = x0 + 1, y1 = y0 + 1;
    int x0c = min(max(x0, 0), WB - 1), x1c = min(max(x1, 0), WB - 1);
    int y0c = min(max(y0, 0), HB - 1), y1c = min(max(y1, 0), HB - 1);
    float vx0 = ((unsigned)x0 < (unsigned)WB) ? 1.f : 0.f;
    float vx1 = ((unsigned)x1 < (unsigned)WB) ? 1.f : 0.f;
    float vy0 = ((unsigned)y0 < (unsigned)HB) ? 1.f : 0.f;
    float vy1 = ((unsigned)y1 < (unsigned)HB) ? 1.f : 0.f;
    const int pb = b * NQ;                 // per-queue pixel plane offset
    int4 ix;
    ix.x = pb + y0c * WB + x0c;
    ix.y = pb + y0c * WB + x1c;
    ix.z = pb + y1c * WB + x0c;
    ix.w = pb + y1c * WB + x1c;
    float4 wv;
    wv.x = aw * (1.f - lx) * (1.f - ly) * vx0 * vy0;
    wv.y = aw * lx * (1.f - ly) * vx1 * vy0;
    wv.z = aw * (1.f - lx) * ly * vx0 * vy1;
    wv.w = aw * lx * ly * vx1 * vy1;
    sidx[e] = ix;
    swgt[e] = wv;
  }
  __syncthreads();

  // gather: thread = (qi, c); reads vh[h][pixel][c*8 .. c*8+8) as uint4
  const int qi = t >> 2, c = t & 3;
  const unsigned short* vb = vh + (size_t)h * HPIX + c * 8;
  float4 lo = {0.f, 0.f, 0.f, 0.f}, hi = lo;
  #pragma unroll
  for (int b = 0; b < 2; b++) {
    #pragma unroll
    for (int p = 0; p < 4; p++) {
      int ent = qi * 8 + b * 4 + p;
      int4 pix = sidx[ent];
      float4 wv = swgt[ent];
      accp(lo, hi, *(const uint4*)(vb + (size_t)pix.x * 32), wv.x);
      accp(lo, hi, *(const uint4*)(vb + (size_t)pix.y * 32), wv.y);
      accp(lo, hi, *(const uint4*)(vb + (size_t)pix.z * 32), wv.z);
      accp(lo, hi, *(const uint4*)(vb + (size_t)pix.w * 32), wv.w);
    }
  }
  union { unsigned short us[8]; uint4 v; } o;
  o.us[0] = f2bf(lo.x); o.us[1] = f2bf(lo.y);
  o.us[2] = f2bf(lo.z); o.us[3] = f2bf(lo.w);
  o.us[4] = f2bf(hi.x); o.us[5] = f2bf(hi.y);
  o.us[6] = f2bf(hi.z); o.us[7] = f2bf(hi.w);
  *(uint4*)(msd + (size_t)h * NQ * 32 + (size_t)(q0 + qi) * 32 + c * 8) = o.v;
}

// ---------------------------------------------------------------------------
// mega: persistent kernel, all 4 stages, 3 manual grid barriers.
// Round-14 rationale: k12=109 but total=337 — k3/k4 each <108 plus 3 launch
// boundaries = ~220 us of serial latency-bound phases with idle ramps/tails.
// One persistent launch removes the boundaries and raises resident waves
// (20/CU vs measured 13 during k12). All bodies byte-identical to round-13.
// __launch_bounds__(256,8) forces VGPR<=64 -> capacity 8 blocks/CU with
// 16.9 KB LDS -> GRID=1280 always co-resident (deadlock-safe).
// ---------------------------------------------------------------------------
__global__ __launch_bounds__(256, 8) void mega(
    const float* __restrict__ value, const float* __restrict__ query,
    const float* __restrict__ qpos, const float* __restrict__ refp,
    const float* __restrict__ W_off, const float* __restrict__ b_off,
    const float* __restrict__ W_attn, const float* __restrict__ b_attn,
    const float* __restrict__ W_val, const float* __restrict__ b_val,
    const float* __restrict__ W_out, const float* __restrict__ b_out,
    unsigned short* __restrict__ raw1, unsigned short* __restrict__ vout,
    unsigned short* __restrict__ msdb, unsigned short* __restrict__ Wc1t,
    unsigned short* __restrict__ Wvt, unsigned short* __restrict__ Wot,
    float* __restrict__ bc1, float* __restrict__ out, unsigned* bar)
{
  __shared__ __align__(16) char lds[16896];
  const int bid = blockIdx.x;
  const int t = threadIdx.x;

  // phase 0: weight conversion (897 tiles)
  for (int tile = bid; tile < 897; tile += GRID)
    conv_body(tile, t, W_off, b_off, W_attn, b_attn, W_val, W_out,
              Wc1t, Wvt, Wot, bc1);
  grid_sync(bar);

  // phase 1: k12 — k1 (tiles 0-1249) + k2 (tiles 1250-3749)
  for (int tile = bid; tile < 3750; tile += GRID) {
    if (tile < 1250)
      gemm_body<512, 192, 2, 1, false>(tile, lds, value, query, qpos,
                                       Wc1t, bc1, nullptr, raw1);
    else
      gemm_body<256, 256, 1, 2, false>(tile - 1250, lds, value, nullptr,
                                       nullptr, Wvt, b_val, nullptr, vout);
    __syncthreads();                       // WAR on lds across tiles
  }
  grid_sync(bar);

  // phase 2: k3 sampling (5000 tiles; GRID%8==0 keeps h=bid&7 per block)
  for (int tile = bid; tile < 5000; tile += GRID) {
    k3_body(tile, lds, raw1, refp, vout, msdb);
    __syncthreads();                       // WAR on lds across tiles
  }
  grid_sync(bar);

  // phase 3: k4 output GEMM (1250 tiles, 1 round)
  for (int tile = bid; tile < 1250; tile += GRID)
    gemm_body<256, 256, 4, 0, true>(tile, lds, msdb, nullptr, nullptr,
                                    Wot, b_out, query, out);
}

// ---------------------------------------------------------------------------
extern "C" void kernel_launch(void* const* d_in, const int* in_sizes, int n_in,
                              void* d_out, int out_size, void* d_ws, size_t ws_size,
                              hipStream_t stream) {
  const float* query     = (const float*)d_in[0];
  const float* query_pos = (const float*)d_in[1];
  const float* value     = (const float*)d_in[2];
  const float* refp      = (const float*)d_in[3];
  // d_in[4]: spatial_shapes constant [200,200]
  const float* W_off  = (const float*)d_in[5];
  const float* b_off  = (const float*)d_in[6];
  const float* W_attn = (const float*)d_in[7];
  const float* b_attn = (const float*)d_in[8];
  const float* W_val  = (const float*)d_in[9];
  const float* b_val  = (const float*)d_in[10];
  const float* W_out  = (const float*)d_in[11];
  const float* b_out  = (const float*)d_in[12];
  float* out = (float*)d_out;

  char* ws = (char*)d_ws;
  unsigned short* raw1 = (unsigned short*)(ws);            // 40000*192*2 = 15,360,000
  unsigned short* vout = (unsigned short*)(ws + 15360000); // 80000*256*2 (head-major)
  unsigned short* msdb = (unsigned short*)(ws + 56320000); // 40000*256*2 (head-major)
  unsigned short* Wc1t = (unsigned short*)(ws + 76800000); // 192*512*2
  unsigned short* Wvt  = (unsigned short*)(ws + 76996608); // 256*256*2
  unsigned short* Wot  = (unsigned short*)(ws + 77127680); // 256*256*2
  float*          bc1  = (float*)(ws + 77258752);          // 192*4
  unsigned*       bar  = (unsigned*)(ws + 77259520);       // grid barrier

  // reset barrier counter every launch (graph-replay / re-poison safe)
  hipMemsetAsync(bar, 0, 4, stream);

  hipLaunchKernelGGL(mega, dim3(GRID), dim3(256), 0, stream,
                     value, query, query_pos, refp,
                     W_off, b_off, W_attn, b_attn, W_val, b_val, W_out, b_out,
                     raw1, vout, msdb, Wc1t, Wvt, Wot, bc1, out, bar);
}

// Round 15
// 824.033 us; speedup vs baseline: 1.4588x; 1.4588x over previous
//
#include <hip/hip_runtime.h>
#include <math.h>

// Problem constants: EMBED=256, HEADS=8, LEVELS=1, POINTS=4, QUEUE=2, 200x200
#define NQ    40000
#define EMB   256
#define NHEAD 8
#define HDIM  32
#define HB    200
#define WB    200
#define NCOL  192     // 128 off cols + 64 aw cols
#define HPIX  2560000 // per-head vout plane: 80000 pixels * 32 dims
#define GRID  1024    // persistent grid: 4 blocks/CU. Co-residency GUARANTEED:
                      // launch_bounds(256,4) -> VGPR cap 128 -> >=4 waves/SIMD;
                      // LDS 16.9 KB -> 9 blocks/CU. min = 4/CU = 1024 blocks.
                      // (Round-14 lesson: (256,8) starved bodies to 32 VGPR ->
                      // 1 GB spill traffic. (256,4) is the bound all bodies
                      // compiled spill-free at 64 VGPR in rounds 12-13.)

typedef __attribute__((ext_vector_type(8))) __bf16 bf16x8;
typedef __attribute__((ext_vector_type(4))) float f32x4;

static __device__ __forceinline__ unsigned short f2bf(float f) {
  unsigned u = __float_as_uint(f);
  u = u + 0x7fffu + ((u >> 16) & 1u);   // round-to-nearest-even
  return (unsigned short)(u >> 16);
}
static __device__ __forceinline__ float bf2f(unsigned short s) {
  return __uint_as_float(((unsigned)s) << 16);
}
// accumulate 8 bf16 (one uint4) into two named float4s (spill-safe)
static __device__ __forceinline__ void accp(float4& lo4, float4& hi4, uint4 u, float w) {
  lo4.x += w * __uint_as_float(u.x << 16);
  lo4.y += w * __uint_as_float(u.x & 0xffff0000u);
  lo4.z += w * __uint_as_float(u.y << 16);
  lo4.w += w * __uint_as_float(u.y & 0xffff0000u);
  hi4.x += w * __uint_as_float(u.z << 16);
  hi4.y += w * __uint_as_float(u.z & 0xffff0000u);
  hi4.z += w * __uint_as_float(u.w << 16);
  hi4.w += w * __uint_as_float(u.w & 0xffff0000u);
}

// ---------------------------------------------------------------------------
// grid_sync: manual all-blocks barrier (monotonic counter, reset to 0 by a
// hipMemsetAsync before each launch -> graph-replay / re-poison safe).
// Device-scope atomics + __threadfence for cross-XCD visibility (G16).
// Safe because GRID (1024) <= guaranteed co-resident capacity (1024).
// Protocol proven correct in round 14 (passed, absmax 0.03125).
// ---------------------------------------------------------------------------
static __device__ __forceinline__ void grid_sync(unsigned* bar) {
  __syncthreads();
  if (threadIdx.x == 0) {
    __threadfence();                       // publish this block's writes
    unsigned my = atomicAdd(bar, 1u) + 1u;
    unsigned tgt = ((my - 1u) / (unsigned)GRID + 1u) * (unsigned)GRID;
    while (atomicAdd(bar, 0u) < tgt) { __builtin_amdgcn_s_sleep(16); }
    __threadfence();                       // acquire others' writes
  }
  __syncthreads();
}

// ---------------------------------------------------------------------------
// conv body: transposed bf16 weights + combined bias (coalesced reads)
// ---------------------------------------------------------------------------
static __device__ __forceinline__ void conv_body(
    int tile, int t,
    const float* __restrict__ W_off, const float* __restrict__ b_off,
    const float* __restrict__ W_attn, const float* __restrict__ b_attn,
    const float* __restrict__ W_val, const float* __restrict__ W_out,
    unsigned short* __restrict__ Wc1t, unsigned short* __restrict__ Wvt,
    unsigned short* __restrict__ Wot, float* __restrict__ bc1)
{
  int idx = tile * 256 + t;
  if (idx < 65536) {                       // W_off [512][128] -> Wc1t[n][k]
    int k = idx >> 7, n = idx & 127;
    Wc1t[(size_t)n * 512 + k] = f2bf(W_off[idx]);
  } else if (idx < 98304) {                // W_attn [512][64] -> Wc1t[128+n][k]
    int j = idx - 65536;
    int k = j >> 6, n = j & 63;
    Wc1t[(size_t)(128 + n) * 512 + k] = f2bf(W_attn[j]);
  } else if (idx < 163840) {               // W_val [256][256] -> Wvt[n][k]
    int j = idx - 98304;
    int k = j >> 8, n = j & 255;
    Wvt[(size_t)n * 256 + k] = f2bf(W_val[j]);
  } else if (idx < 229376) {               // W_out [256][256] -> Wot[n][k]
    int j = idx - 163840;
    int k = j >> 8, n = j & 255;
    Wot[(size_t)n * 256 + k] = f2bf(W_out[j]);
  } else if (idx < 229568) {               // bc1 [192]
    int n = idx - 229376;
    bc1[n] = (n < 128) ? b_off[n] : b_attn[n - 128];
  }
}

// ---------------------------------------------------------------------------
// GEMM body (round-12/13 verified, BM=32). C[32 x N] = A @ Bt^T + bias.
// Block = 4 waves 1m x 4n. Staged A: 32x256 bf16 LDS half-tile (16.4 KB),
// XOR-swizzled 16B chunks (slot = c ^ (r&7)); K=512 stages two halves.
// Staged sources are [M][256] fp32: stride 256 ALWAYS (hh selects WHICH
// tensor, never a column offset — round-11 lesson).
// AMODE 1 = fp32 staged; 2 = synth q2 staged (half0 value, half1 q+qp);
// 0 = bf16 [M][K] direct; 4 = bf16 head-major [h][NQ][32] direct.
// OMODE 0 = fp32 direct (+resid); 1 = bf16 row-major; 2 = bf16 head-major.
// BM=32 stays (round-10: BM=16 doubled B-load per MFMA).
// ---------------------------------------------------------------------------
template<int K, int N, int AMODE, int OMODE, bool RESID>
static __device__ __forceinline__ void gemm_body(
    int bx, char* lds,
    const void* __restrict__ Aptr, const void* __restrict__ Aq2a,
    const void* __restrict__ Aq2b, const unsigned short* __restrict__ Bt,
    const float* __restrict__ bias, const float* __restrict__ resid,
    void* __restrict__ outp)
{
  constexpr int NFR = N / 64;              // 16-col n-frags per wave
  constexpr int NP  = N + 8;
  unsigned short* trn = (unsigned short*)lds;

  const int t = threadIdx.x;
  const int m0 = bx * 32;
  const int wid = t >> 6, lane = t & 63;
  const int wn = wid * (N / 4);
  const int lr = lane & 15, quad = lane >> 4;

  auto cvt_store = [&](int r, int c, float4 f0, float4 f1) {
    union { unsigned short us[8]; uint4 v; } u;
    u.us[0] = f2bf(f0.x); u.us[1] = f2bf(f0.y);
    u.us[2] = f2bf(f0.z); u.us[3] = f2bf(f0.w);
    u.us[4] = f2bf(f1.x); u.us[5] = f2bf(f1.y);
    u.us[6] = f2bf(f1.z); u.us[7] = f2bf(f1.w);
    *(uint4*)(lds + (size_t)r * 512 + ((c ^ (r & 7)) * 16)) = u.v;
  };

  // stage one 256-wide K-half (hh): thread owns col-chunk c = t&31,
  // rows r0 + 8l; ALL loads issued before any convert (one HBM exposure).
  auto stage_h = [&](int hh) {
    const int c = t & 31, r0 = t >> 5;
    if (AMODE == 1 || hh == 0) {
      float4 f[4][2];
      #pragma unroll
      for (int l = 0; l < 4; l++) {
        const float* s = (const float*)Aptr
            + (size_t)(m0 + r0 + 8 * l) * 256 + c * 8;
        f[l][0] = *(const float4*)s; f[l][1] = *(const float4*)(s + 4);
      }
      #pragma unroll
      for (int l = 0; l < 4; l++)
        cvt_store(r0 + 8 * l, c, f[l][0], f[l][1]);
    } else {
      float4 fq[4][2], fp[4][2];
      #pragma unroll
      for (int l = 0; l < 4; l++) {
        int row = m0 + r0 + 8 * l;
        const float* sq = (const float*)Aq2a + (size_t)row * 256 + c * 8;
        const float* sp = (const float*)Aq2b + (size_t)row * 256 + c * 8;
        fq[l][0] = *(const float4*)sq; fq[l][1] = *(const float4*)(sq + 4);
        fp[l][0] = *(const float4*)sp; fp[l][1] = *(const float4*)(sp + 4);
      }
      #pragma unroll
      for (int l = 0; l < 4; l++) {
        float4 f0 = make_float4(fq[l][0].x + fp[l][0].x, fq[l][0].y + fp[l][0].y,
                                fq[l][0].z + fp[l][0].z, fq[l][0].w + fp[l][0].w);
        float4 f1 = make_float4(fq[l][1].x + fp[l][1].x, fq[l][1].y + fp[l][1].y,
                                fq[l][1].z + fp[l][1].z, fq[l][1].w + fp[l][1].w);
        cvt_store(r0 + 8 * l, c, f0, f1);
      }
    }
  };

  f32x4 acc[2][NFR];
  #pragma unroll
  for (int i = 0; i < 2; i++)
    #pragma unroll
    for (int n = 0; n < NFR; n++) acc[i][n] = (f32x4){0.f, 0.f, 0.f, 0.f};

  auto loadB = [&](bf16x8* dst, int k0) {  // k0 = global K offset
    #pragma unroll
    for (int n = 0; n < NFR; n++)
      dst[n] = *(const bf16x8*)(Bt + (size_t)(wn + n * 16 + lr) * K + k0 + quad * 8);
  };
  auto loadA_lds = [&](bf16x8* dst, int lk) {  // lk = offset within half
    const int cb = (lk >> 3) + quad;
    const int sw = (cb ^ (lr & 7)) * 16;
    #pragma unroll
    for (int i = 0; i < 2; i++)
      dst[i] = *(const bf16x8*)(lds + (size_t)(lr + i * 16) * 512 + sw);
  };
  auto loadA_dir = [&](bf16x8* dst, int k0) {
    if constexpr (AMODE == 0) {
      const unsigned short* A = (const unsigned short*)Aptr;
      #pragma unroll
      for (int i = 0; i < 2; i++)
        dst[i] = *(const bf16x8*)(A + (size_t)(m0 + lr + i * 16) * K + k0 + quad * 8);
    } else {                               // AMODE == 4: head-major
      const unsigned short* A = (const unsigned short*)Aptr;
      const int h = k0 >> 5;
      #pragma unroll
      for (int i = 0; i < 2; i++)
        dst[i] = *(const bf16x8*)(A + (size_t)h * NQ * 32
                                    + (size_t)(m0 + lr + i * 16) * 32 + quad * 8);
    }
  };

  if constexpr (AMODE == 1 || AMODE == 2) {
    constexpr int NH = K / 256;            // staged halves
    #pragma unroll
    for (int hh = 0; hh < NH; hh++) {
      if (hh) __syncthreads();             // WAR: prev half reads done
      stage_h(hh);
      __syncthreads();
      bf16x8 b0[NFR], b1[NFR], af[2];
      loadB(b0, hh * 256);
      loadB(b1, hh * 256 + 32);
      loadA_lds(af, 0);
      #pragma unroll
      for (int ks = 0; ks < 8; ks++) {
        bf16x8 b2[NFR], an[2];
        if (ks + 2 < 8) loadB(b2, hh * 256 + (ks + 2) * 32);
        if (ks + 1 < 8) loadA_lds(an, (ks + 1) * 32);
        #pragma unroll
        for (int i = 0; i < 2; i++)
          #pragma unroll
          for (int n = 0; n < NFR; n++)
            acc[i][n] = __builtin_amdgcn_mfma_f32_16x16x32_bf16(af[i], b0[n], acc[i][n], 0, 0, 0);
        #pragma unroll
        for (int n = 0; n < NFR; n++) { b0[n] = b1[n]; b1[n] = b2[n]; }
        af[0] = an[0]; af[1] = an[1];
      }
    }
  } else {
    constexpr int NK = K / 32;
    bf16x8 b0[NFR], b1[NFR], af[2];
    loadB(b0, 0);
    if (NK > 1) loadB(b1, 32);
    loadA_dir(af, 0);
    #pragma unroll
    for (int ks = 0; ks < NK; ks++) {
      bf16x8 b2[NFR], an[2];
      if (ks + 2 < NK) loadB(b2, (ks + 2) * 32);
      if (ks + 1 < NK) loadA_dir(an, (ks + 1) * 32);
      #pragma unroll
      for (int i = 0; i < 2; i++)
        #pragma unroll
        for (int n = 0; n < NFR; n++)
          acc[i][n] = __builtin_amdgcn_mfma_f32_16x16x32_bf16(af[i], b0[n], acc[i][n], 0, 0, 0);
      #pragma unroll
      for (int n = 0; n < NFR; n++) { b0[n] = b1[n]; b1[n] = b2[n]; }
      af[0] = an[0]; af[1] = an[1];
    }
  }

  // epilogue: C/D layout col=lane&15, row=quad*4+reg
  if constexpr (OMODE == 0) {
    #pragma unroll
    for (int i = 0; i < 2; i++) {
      int rowb = m0 + i * 16 + quad * 4;
      #pragma unroll
      for (int n = 0; n < NFR; n++) {
        int col = wn + n * 16 + lr;
        float bsv = bias[col];
        #pragma unroll
        for (int r = 0; r < 4; r++) {
          int rr = rowb + r;
          float v = acc[i][n][r] + bsv;
          if (RESID) v += resid[(size_t)rr * N + col];
          ((float*)outp)[(size_t)rr * N + col] = v;
        }
      }
    }
  } else {
    __syncthreads();                       // A-tile -> trn buffer reuse
    #pragma unroll
    for (int i = 0; i < 2; i++) {
      #pragma unroll
      for (int n = 0; n < NFR; n++) {
        int col = wn + n * 16 + lr;
        float bsv = bias[col];
        #pragma unroll
        for (int r = 0; r < 4; r++) {
          int rl = i * 16 + quad * 4 + r;
          trn[rl * NP + col] = f2bf(acc[i][n][r] + bsv);
        }
      }
    }
    __syncthreads();
    constexpr int NCH = (32 * N) / 2048;   // uint4 chunks per thread
    #pragma unroll
    for (int l = 0; l < NCH; l++) {
      int c = t + l * 256;
      int row = c / (N / 8);
      int coloff = (c % (N / 8)) * 8;
      uint4 d = *(const uint4*)(trn + row * NP + coloff);
      unsigned short* op = (unsigned short*)outp;
      if constexpr (OMODE == 2)
        op += (size_t)(coloff >> 5) * HPIX + (size_t)(m0 + row) * 32 + (coloff & 31);
      else
        op += (size_t)(m0 + row) * N + coloff;
      *(uint4*)op = d;
    }
  }
}

// ---------------------------------------------------------------------------
// k3 body: deformable sampling + queue mean, HEAD<->XCD AFFINE (round-8
// verified). tile = qg*8 + h; with GRID % 8 == 0 the grid-stride keeps
// h = bid&7 constant per block -> per-XCD 5 MB head plane stays L2-affine.
// sidx/swgt live in the caller's LDS buffer (16 KB <= 16.9 KB).
// ---------------------------------------------------------------------------
static __device__ __forceinline__ void k3_body(
    int tile, char* lds,
    const unsigned short* __restrict__ raw1, const float* __restrict__ refp,
    const unsigned short* __restrict__ vh, unsigned short* __restrict__ msd)
{
  int4*   sidx = (int4*)lds;               // [512] = 8 KB
  float4* swgt = (float4*)(lds + 8192);    // [512] = 8 KB
  const int t = threadIdx.x;
  const int h  = tile & 7;                 // head = XCD slot
  const int q0 = (tile >> 3) * 64;         // 625 query-groups x 8 heads

  #pragma unroll
  for (int ee = 0; ee < 2; ee++) {
    const int e = t + ee * 256;            // e = qi*8 + b*4 + p
    const int qi = e >> 3, b = (e >> 2) & 1, p = e & 3;
    const int q = q0 + qi;
    const unsigned short* r = raw1 + (size_t)q * NCOL;
    float ox = bf2f(r[h * 16 + b * 8 + p * 2 + 0]);
    float oy = bf2f(r[h * 16 + b * 8 + p * 2 + 1]);
    float l0 = bf2f(r[128 + h * 8 + b * 4 + 0]);
    float l1 = bf2f(r[128 + h * 8 + b * 4 + 1]);
    float l2 = bf2f(r[128 + h * 8 + b * 4 + 2]);
    float l3 = bf2f(r[128 + h * 8 + b * 4 + 3]);
    float mx = fmaxf(fmaxf(l0, l1), fmaxf(l2, l3));
    float e0 = expf(l0 - mx), e1 = expf(l1 - mx);
    float e2 = expf(l2 - mx), e3 = expf(l3 - mx);
    float ssum = e0 + e1 + e2 + e3;
    float ep = (p == 0) ? e0 : (p == 1) ? e1 : (p == 2) ? e2 : e3;
    float aw = ep / ssum * 0.5f;           // fold queue-mean 0.5
    float rx = refp[((size_t)b * NQ + q) * 2 + 0];
    float ry = refp[((size_t)b * NQ + q) * 2 + 1];
    float px = rx * (float)WB + ox - 0.5f;
    float py = ry * (float)HB + oy - 0.5f;
    float x0f = floorf(px), y0f = floorf(py);
    float lx = px - x0f, ly = py - y0f;
    int x0 = (int)x0f, y0 = (int)y0f, x1 = x0 + 1, y1 = y0 + 1;
    int x0c = min(max(x0, 0), WB - 1), x1c = min(max(x1, 0), WB - 1);
    int y0c = min(max(y0, 0), HB - 1), y1c = min(max(y1, 0), HB - 1);
    float vx0 = ((unsigned)x0 < (unsigned)WB) ? 1.f : 0.f;
    float vx1 = ((unsigned)x1 < (unsigned)WB) ? 1.f : 0.f;
    float vy0 = ((unsigned)y0 < (unsigned)HB) ? 1.f : 0.f;
    float vy1 = ((unsigned)y1 < (unsigned)HB) ? 1.f : 0.f;
    const int pb = b * NQ;                 // per-queue pixel plane offset
    int4 ix;
    ix.x = pb + y0c * WB + x0c;
    ix.y = pb + y0c * WB + x1c;
    ix.z = pb + y1c * WB + x0c;
    ix.w = pb + y1c * WB + x1c;
    float4 wv;
    wv.x = aw * (1.f - lx) * (1.f - ly) * vx0 * vy0;
    wv.y = aw * lx * (1.f - ly) * vx1 * vy0;
    wv.z = aw * (1.f - lx) * ly * vx0 * vy1;
    wv.w = aw * lx * ly * vx1 * vy1;
    sidx[e] = ix;
    swgt[e] = wv;
  }
  __syncthreads();

  // gather: thread = (qi, c); reads vh[h][pixel][c*8 .. c*8+8) as uint4
  const int qi = t >> 2, c = t & 3;
  const unsigned short* vb = vh + (size_t)h * HPIX + c * 8;
  float4 lo = {0.f, 0.f, 0.f, 0.f}, hi = lo;
  #pragma unroll
  for (int b = 0; b < 2; b++) {
    #pragma unroll
    for (int p = 0; p < 4; p++) {
      int ent = qi * 8 + b * 4 + p;
      int4 pix = sidx[ent];
      float4 wv = swgt[ent];
      accp(lo, hi, *(const uint4*)(vb + (size_t)pix.x * 32), wv.x);
      accp(lo, hi, *(const uint4*)(vb + (size_t)pix.y * 32), wv.y);
      accp(lo, hi, *(const uint4*)(vb + (size_t)pix.z * 32), wv.z);
      accp(lo, hi, *(const uint4*)(vb + (size_t)pix.w * 32), wv.w);
    }
  }
  union { unsigned short us[8]; uint4 v; } o;
  o.us[0] = f2bf(lo.x); o.us[1] = f2bf(lo.y);
  o.us[2] = f2bf(lo.z); o.us[3] = f2bf(lo.w);
  o.us[4] = f2bf(hi.x); o.us[5] = f2bf(hi.y);
  o.us[6] = f2bf(hi.z); o.us[7] = f2bf(hi.w);
  *(uint4*)(msd + (size_t)h * NQ * 32 + (size_t)(q0 + qi) * 32 + c * 8) = o.v;
}

// ---------------------------------------------------------------------------
// mega: persistent kernel, all 4 stages, 3 manual grid barriers.
// Round-15: identical to round-14 EXCEPT __launch_bounds__(256,4) + GRID=1024
// (round-14's (256,8) starved bodies to 32 VGPR -> 1 GB scratch spill,
// MfmaUtil 0.9%). (256,4) = the bound all bodies compiled spill-free at
// 64 VGPR in rounds 12-13. Removes 3 launch boundaries + ramps/tails.
// ---------------------------------------------------------------------------
__global__ __launch_bounds__(256, 4) void mega(
    const float* __restrict__ value, const float* __restrict__ query,
    const float* __restrict__ qpos, const float* __restrict__ refp,
    const float* __restrict__ W_off, const float* __restrict__ b_off,
    const float* __restrict__ W_attn, const float* __restrict__ b_attn,
    const float* __restrict__ W_val, const float* __restrict__ b_val,
    const float* __restrict__ W_out, const float* __restrict__ b_out,
    unsigned short* __restrict__ raw1, unsigned short* __restrict__ vout,
    unsigned short* __restrict__ msdb, unsigned short* __restrict__ Wc1t,
    unsigned short* __restrict__ Wvt, unsigned short* __restrict__ Wot,
    float* __restrict__ bc1, float* __restrict__ out, unsigned* bar)
{
  __shared__ __align__(16) char lds[16896];
  const int bid = blockIdx.x;
  const int t = threadIdx.x;

  // phase 0: weight conversion (897 tiles)
  for (int tile = bid; tile < 897; tile += GRID)
    conv_body(tile, t, W_off, b_off, W_attn, b_attn, W_val, W_out,
              Wc1t, Wvt, Wot, bc1);
  grid_sync(bar);

  // phase 1: k12 — k1 (tiles 0-1249) + k2 (tiles 1250-3749)
  for (int tile = bid; tile < 3750; tile += GRID) {
    if (tile < 1250)
      gemm_body<512, 192, 2, 1, false>(tile, lds, value, query, qpos,
                                       Wc1t, bc1, nullptr, raw1);
    else
      gemm_body<256, 256, 1, 2, false>(tile - 1250, lds, value, nullptr,
                                       nullptr, Wvt, b_val, nullptr, vout);
    __syncthreads();                       // WAR on lds across tiles
  }
  grid_sync(bar);

  // phase 2: k3 sampling (5000 tiles; GRID%8==0 keeps h=bid&7 per block)
  for (int tile = bid; tile < 5000; tile += GRID) {
    k3_body(tile, lds, raw1, refp, vout, msdb);
    __syncthreads();                       // WAR on lds across tiles
  }
  grid_sync(bar);

  // phase 3: k4 output GEMM (1250 tiles)
  for (int tile = bid; tile < 1250; tile += GRID)
    gemm_body<256, 256, 4, 0, true>(tile, lds, msdb, nullptr, nullptr,
                                    Wot, b_out, query, out);
}

// ---------------------------------------------------------------------------
extern "C" void kernel_launch(void* const* d_in, const int* in_sizes, int n_in,
                              void* d_out, int out_size, void* d_ws, size_t ws_size,
                              hipStream_t stream) {
  const float* query     = (const float*)d_in[0];
  const float* query_pos = (const float*)d_in[1];
  const float* value     = (const float*)d_in[2];
  const float* refp      = (const float*)d_in[3];
  // d_in[4]: spatial_shapes constant [200,200]
  const float* W_off  = (const float*)d_in[5];
  const float* b_off  = (const float*)d_in[6];
  const float* W_attn = (const float*)d_in[7];
  const float* b_attn = (const float*)d_in[8];
  const float* W_val  = (const float*)d_in[9];
  const float* b_val  = (const float*)d_in[10];
  const float* W_out  = (const float*)d_in[11];
  const float* b_out  = (const float*)d_in[12];
  float* out = (float*)d_out;

  char* ws = (char*)d_ws;
  unsigned short* raw1 = (unsigned short*)(ws);            // 40000*192*2 = 15,360,000
  unsigned short* vout = (unsigned short*)(ws + 15360000); // 80000*256*2 (head-major)
  unsigned short* msdb = (unsigned short*)(ws + 56320000); // 40000*256*2 (head-major)
  unsigned short* Wc1t = (unsigned short*)(ws + 76800000); // 192*512*2
  unsigned short* Wvt  = (unsigned short*)(ws + 76996608); // 256*256*2
  unsigned short* Wot  = (unsigned short*)(ws + 77127680); // 256*256*2
  float*          bc1  = (float*)(ws + 77258752);          // 192*4
  unsigned*       bar  = (unsigned*)(ws + 77259520);       // grid barrier

  // reset barrier counter every launch (graph-replay / re-poison safe)
  hipMemsetAsync(bar, 0, 4, stream);

  hipLaunchKernelGGL(mega, dim3(GRID), dim3(256), 0, stream,
                     value, query, query_pos, refp,
                     W_off, b_off, W_attn, b_attn, W_val, b_val, W_out, b_out,
                     raw1, vout, msdb, Wc1t, Wvt, Wot, bc1, out, bar);
}